// Round 10
// baseline (261.438 us; speedup 1.0000x reference)
//
#include <hip/hip_runtime.h>
#include <stdint.h>

typedef unsigned short u16;
typedef __attribute__((ext_vector_type(8))) __bf16 bf16x8;
typedef __attribute__((ext_vector_type(4))) float f32x4;
typedef __attribute__((ext_vector_type(2))) unsigned int uint32x2;

#define DIM 1024
#define NH 16
#define HD 64
#define BSZ 2
#define LQ 2048
#define LK 2048
// SCALE * log2(e) = 0.125 * 1.4426950408889634
#define SCALE_LOG2E 0.18033688011112043f
#define MNEG -3.0e38f

// DTYPE TRUTH (established rounds 1-8): d_in float tensors and d_out are
// FP32. Reading them as bf16 produces NaN-pattern u16s (rounds 1,7,8 NaN).
// Internal pipeline is bf16 via an explicit convert pass.

static __device__ __forceinline__ float b2f(u16 u) {
  union { uint32_t i; float f; } v; v.i = ((uint32_t)u) << 16; return v.f;
}
static __device__ __forceinline__ u16 f2b(float f) {
  uint32_t x = __float_as_uint(f);
  return (u16)((x + 0x7fffu + ((x >> 16) & 1u)) >> 16);
}
// bf16 pair pack, round-half-up: 2 adds + 1 v_perm_b32 (validated r5-r6)
static __device__ __forceinline__ uint32_t pk2r(float lo, float hi) {
  uint32_t a = __float_as_uint(lo) + 0x8000u;
  uint32_t b = __float_as_uint(hi) + 0x8000u;
  return __builtin_amdgcn_perm(b, a, 0x07060302u);  // lo16=a[31:16], hi16=b[31:16]
}
// R10: single-instruction packed f32->bf16x2 (RNE). Plain VOP3, no hazard.
static __device__ __forceinline__ uint32_t cvtpk(float lo, float hi) {
  uint32_t r;
  asm("v_cvt_pk_bf16_f32 %0, %1, %2" : "=v"(r) : "v"(lo), "v"(hi));
  return r;
}
static __device__ __forceinline__ f32x4 zero4() {
  f32x4 z; z[0] = 0.f; z[1] = 0.f; z[2] = 0.f; z[3] = 0.f; return z;
}
// exp2 via raw v_exp_f32 (library exp2f = ~10+ instrs of fixup; R4).
// s_nop inside the asm covers the TRANS->consumer 1-waitstate hazard.
// fmin guard: inf insurance; masked -3e38 still -> 0 exactly.
static __device__ __forceinline__ float exp2c(float s) {
  float r;
  asm("v_exp_f32 %0, %1\n\ts_nop 0" : "=v"(r) : "v"(fminf(s, 30.0f)));
  return r;
}
// async global->LDS, 16B/lane; LDS dest is wave-uniform base + lane*16
static __device__ __forceinline__ void gload_lds16(const u16* g, u16* l) {
  __builtin_amdgcn_global_load_lds(
      (const __attribute__((address_space(1))) void*)g,
      (__attribute__((address_space(3))) void*)l, 16, 0, 0);
}

// ---------- kv_mask all-valid reduction (per batch) ----------
__global__ void mask_allvalid(const int* __restrict__ kvmask, int* allv) {
  int b = blockIdx.x;
  int base = b * LK + threadIdx.x * 8;
  int ok = 1;
#pragma unroll
  for (int j = 0; j < 8; ++j) ok &= (kvmask[base + j] != 0);
  unsigned long long m = __ballot(ok != 0);
  if ((threadIdx.x & 63) == 0 && m != ~0ULL) atomicAnd(&allv[b], 0);
}

// ---------- input canonicalization: fp32 -> bf16 in ws ----------
struct ConvArgs {
  const float* src[11];
  long long cum[12];   // cumulative element offsets (all sizes % 8 == 0)
  u16* dst;
};

__global__ void convert_inputs(ConvArgs ca) {
  long long c = (long long)blockIdx.x * blockDim.x + threadIdx.x;
  long long e0 = c * 8;
  if (e0 >= ca.cum[11]) return;
  int s = 0;
  while (e0 >= ca.cum[s + 1]) ++s;
  const float* sp = ca.src[s] + (e0 - ca.cum[s]);
  union { uint4 v; uint32_t w[4]; } t;
#pragma unroll
  for (int j = 0; j < 4; ++j) t.w[j] = pk2r(sp[2 * j], sp[2 * j + 1]);
  *(uint4*)(ca.dst + e0) = t.v;
}

// ---------- GEMM: Y[m,n] = (sum_k X[m,k]*W[n,k] + bias[n]) * osc ----------
// 128x128 tile, BK=64, 4 waves 2x2, global_load_lds width-16 staging (m97).
struct GemmArgs {
  const u16* X[3];
  const u16* W[3];
  const u16* Bias[3];
  void* Y[3];
  float osc[3];      // output scale; SCALE_LOG2E for Q (softmax in log2 domain)
  int f32out;        // 1 => Y is float* (final output), else bf16 u16*
  int vtz;           // z index whose output is stored as [b][h][d][key]
};

__global__ __launch_bounds__(256, 2) void gemm_bt_bias(GemmArgs ga) {
  const int K = DIM, N = DIM;
  __shared__ u16 smem[17408];          // Al(8K u16) + Bl(8K u16) | VT(128x136)
  u16* const Al = smem;
  u16* const Bl = smem + 8192;
  const int tid = threadIdx.x;
  const int wave = tid >> 6, lane = tid & 63;
  const int wm = wave >> 1, wn = wave & 1;
  const int lrow = lane & 15, quad = lane >> 4;
  const int z = blockIdx.z;
  const u16* X = ga.X[z];
  const u16* W = ga.W[z];
  const u16* Bias = ga.Bias[z];
  const float osc = ga.osc[z];
  const int m0 = blockIdx.x * 128;
  const int n0 = blockIdx.y * 128;

  f32x4 acc[4][4];
#pragma unroll
  for (int i = 0; i < 4; ++i)
#pragma unroll
    for (int j = 0; j < 4; ++j) acc[i][j] = zero4();

  const int cbase = wave * 256;
  for (int k0 = 0; k0 < K; k0 += 64) {
    __syncthreads();  // previous tile fully consumed
#pragma unroll
    for (int i = 0; i < 4; ++i) {
      int c = cbase + i * 64 + lane;       // chunk id, 16B each
      int row = c >> 3, colb = c & 7;
      gload_lds16(X + (size_t)(m0 + row) * K + k0 + colb * 8,
                  &Al[(cbase + i * 64) * 8]);
      gload_lds16(W + (size_t)(n0 + row) * K + k0 + colb * 8,
                  &Bl[(cbase + i * 64) * 8]);
    }
    __syncthreads();  // barrier drains vmcnt -> staged data visible
#pragma unroll
    for (int ks = 0; ks < 2; ++ks) {
      bf16x8 af[4], bfr[4];
#pragma unroll
      for (int t = 0; t < 4; ++t)
        af[t] = *(const bf16x8*)&Al[(wm * 64 + t * 16 + lrow) * 64 + ks * 32 + quad * 8];
#pragma unroll
      for (int t = 0; t < 4; ++t)
        bfr[t] = *(const bf16x8*)&Bl[(wn * 64 + t * 16 + lrow) * 64 + ks * 32 + quad * 8];
#pragma unroll
      for (int mt = 0; mt < 4; ++mt)
#pragma unroll
        for (int nt = 0; nt < 4; ++nt)
          acc[mt][nt] = __builtin_amdgcn_mfma_f32_16x16x32_bf16(af[mt], bfr[nt], acc[mt][nt], 0, 0, 0);
    }
  }

  if (z == ga.vtz) {
    // V projection -> [b][h][d][key]: transpose tile in LDS, coalesced store
    u16* Yv = (u16*)ga.Y[z];
    u16* const VT = smem;  // [128 cols][136 pad] u16
    __syncthreads();       // all waves done reading Al/Bl
#pragma unroll
    for (int nt = 0; nt < 4; ++nt) {
      int colL = wn * 64 + nt * 16 + lrow;
      float bv = b2f(Bias[n0 + colL]);
#pragma unroll
      for (int mt = 0; mt < 4; ++mt) {
        int keyL = wm * 64 + mt * 16 + quad * 4;
        uint2 w;
        w.x = pk2r((acc[mt][nt][0] + bv) * osc, (acc[mt][nt][1] + bv) * osc);
        w.y = pk2r((acc[mt][nt][2] + bv) * osc, (acc[mt][nt][3] + bv) * osc);
        *(uint2*)&VT[colL * 136 + keyL] = w;
      }
    }
    __syncthreads();
    const int bb = m0 >> 11, key0 = m0 & 2047;
#pragma unroll
    for (int i = 0; i < 8; ++i) {       // 8*256 = 2048 chunks = full 128x128
      int c = i * 256 + tid;
      int colL = c >> 4, k8 = c & 15;
      int hh = (n0 + colL) >> 6, dd = (n0 + colL) & 63;
      *(uint4*)(Yv + ((size_t)(bb * NH + hh) * HD + dd) * LK + key0 + k8 * 8) =
          *(const uint4*)&VT[colL * 136 + k8 * 8];
    }
  } else if (ga.f32out) {
    float* Yf = (float*)ga.Y[z];
#pragma unroll
    for (int nt = 0; nt < 4; ++nt) {
      int col = n0 + wn * 64 + nt * 16 + lrow;
      float bv = b2f(Bias[col]);
#pragma unroll
      for (int mt = 0; mt < 4; ++mt) {
        int rowb = m0 + wm * 64 + mt * 16 + quad * 4;
#pragma unroll
        for (int r = 0; r < 4; ++r)
          Yf[(size_t)(rowb + r) * N + col] = (acc[mt][nt][r] + bv) * osc;
      }
    }
  } else {
    u16* Yv = (u16*)ga.Y[z];
#pragma unroll
    for (int nt = 0; nt < 4; ++nt) {
      int col = n0 + wn * 64 + nt * 16 + lrow;
      float bv = b2f(Bias[col]);
#pragma unroll
      for (int mt = 0; mt < 4; ++mt) {
        int rowb = m0 + wm * 64 + mt * 16 + quad * 4;
#pragma unroll
        for (int r = 0; r < 4; ++r)
          Yv[(size_t)(rowb + r) * N + col] = f2b((acc[mt][nt][r] + bv) * osc);
      }
    }
  }
}

// ---------- fused flash attention (S^T formulation, no-max softmax) ----------
// 1 block per (b, h, 128 q rows, key-split); 4 waves x 32 q rows; 128-key
// chunks. Q pre-scaled by SCALE*log2e -> sacc is log2-domain; |s| <~ 3 so
// fixed-max softmax is safe: p = exp2(s); masked keys add -3e38 -> p = 0.
//
// R10 (tail + VALU cuts on R9's confirmed 62.7us):
//  * R9 residuals: VALUBusy 49 (top pipe), occ 23% vs 37.5% cap (drain tail
//    of 8-chunk blocks). nsplit=4 (kspan=512, grid 2048): per-block time
//    halves -> tail halves. Merge is nsplit-way linear (no-max softmax).
//    Guarded ws cascade 4 -> 2 -> 1.
//  * softmax pack: pk2r (3 VALU ops) -> v_cvt_pk_bf16_f32 (1 op, RNE);
//    saves ~64 VALU ops per chunk-wave (~20% of softmax VALU).
//  * Keeps R8/R9: async gload_lds staging, both-sides XOR swizzle (0 bank
//    conflicts), (256,3) = largest spill-free residency.
__global__ __launch_bounds__(256, 3) void attn_fused(
    const u16* __restrict__ qp, const u16* __restrict__ kp,
    const u16* __restrict__ vpt, const int* __restrict__ kvmask,
    const int* __restrict__ allv, u16* __restrict__ op,
    float* __restrict__ opart, float* __restrict__ lpart,
    int nsplit, int kspan) {
  __shared__ u16 Kl[128 * 64];        // K chunk [key][d], LINEAR, XOR-swizzled
  __shared__ u16 Vt[64 * 128];        // V^T chunk [d][key], LINEAR, XOR-swizzled
  __shared__ float Ml[128];           // additive mask per key (masked path)
  const int tid = threadIdx.x;
  const int wave = tid >> 6, lane = tid & 63;
  const int lrow = lane & 15, quad = lane >> 4;
  const int bh = blockIdx.y;
  const int b = bh >> 4, h = bh & 15;
  const int q0 = blockIdx.x * 128;
  const int kc0 = blockIdx.z * kspan;
  const int kcend = kc0 + kspan;
  const bool av = (allv[b] != 0);     // wave-uniform

  const u16* qbase = qp + (size_t)b * LQ * DIM + h * HD;
  const u16* kbase = kp + (size_t)b * LK * DIM + h * HD;
  const u16* vtb = vpt + (size_t)(b * NH + h) * HD * LK;  // [64][2048]
  const int* mbase = kvmask + b * LK;
  const int wq0 = q0 + wave * 32;

  // Q as B-operand frags: B[k=d=quad*8+j][n=q=lrow]
  bf16x8 qf[2][2];
#pragma unroll
  for (int mt = 0; mt < 2; ++mt)
#pragma unroll
    for (int ks = 0; ks < 2; ++ks)
      qf[mt][ks] = *(const bf16x8*)(qbase + (size_t)(wq0 + mt * 16 + lrow) * DIM + ks * 32 + quad * 8);

  f32x4 acco[2][4];
  float lsum[2];
#pragma unroll
  for (int mt = 0; mt < 2; ++mt) {
#pragma unroll
    for (int dt = 0; dt < 4; ++dt) acco[mt][dt] = zero4();
    lsum[mt] = 0.0f;
  }

  // --- staging geometry (all per-thread constants) ---
  // K: instr i covers rows (i*4+wave)*8 + (lane>>3); lane unit u=lane&7,
  //    swizzled source column (u ^ (lane>>3)) since row&7 == lane>>3.
  const u16* kcur = kbase + (size_t)kc0 * DIM
      + (size_t)(wave * 8 + (lane >> 3)) * DIM + (((lane & 7) ^ (lane >> 3)) * 8);
  // V: instr i covers rows (i*4+wave)*4 + (lane>>4); unit u=lane&15,
  //    d&15 == (4*wave + (lane>>4)) & 15 for all i (16i == 0 mod 16).
  const u16* vcur = vtb + kc0
      + (size_t)(wave * 4 + (lane >> 4)) * LK
      + (((lane & 15) ^ ((4 * wave + (lane >> 4)) & 15)) * 8);
  u16* const Kldst = &Kl[wave * 512];   // + i*2048 per instr
  u16* const Vtdst = &Vt[wave * 512];
  // read-side swizzled column bases (u16 units)
  const int kread0 = lrow * 64 + ((quad ^ (lrow & 7)) * 8);
  const int kread1 = lrow * 64 + (((4 + quad) ^ (lrow & 7)) * 8);

  for (int kc = kc0; kc < kcend; kc += 128) {
    // ---- async staging: 8 gload_lds16/thread, ZERO staging VGPRs ----
    gload_lds16(kcur,                       Kldst);
    gload_lds16(kcur + (size_t)32 * DIM,    Kldst + 2048);
    gload_lds16(kcur + (size_t)64 * DIM,    Kldst + 4096);
    gload_lds16(kcur + (size_t)96 * DIM,    Kldst + 6144);
    gload_lds16(vcur,                       Vtdst);
    gload_lds16(vcur + (size_t)16 * LK,     Vtdst + 2048);
    gload_lds16(vcur + (size_t)32 * LK,     Vtdst + 4096);
    gload_lds16(vcur + (size_t)48 * LK,     Vtdst + 6144);
    if (!av && tid < 128) Ml[tid] = mbase[kc + tid] ? 0.0f : MNEG;
    __syncthreads();  // drains vmcnt+lgkm -> staged chunk visible

    // ---- fused S + softmax + PV per 32-key block; P stays in registers ----
#pragma unroll
    for (int kb = 0; kb < 4; ++kb) {
      f32x4 sacc[2][2];
#pragma unroll
      for (int mt = 0; mt < 2; ++mt)
#pragma unroll
        for (int ntl = 0; ntl < 2; ++ntl) sacc[mt][ntl] = zero4();
#pragma unroll
      for (int ks = 0; ks < 2; ++ks) {
#pragma unroll
        for (int ntl = 0; ntl < 2; ++ntl) {
          bf16x8 kf = *(const bf16x8*)&Kl[(2 * kb + ntl) * 1024 + (ks ? kread1 : kread0)];
          sacc[0][ntl] = __builtin_amdgcn_mfma_f32_16x16x32_bf16(kf, qf[0][ks], sacc[0][ntl], 0, 0, 0);
          sacc[1][ntl] = __builtin_amdgcn_mfma_f32_16x16x32_bf16(kf, qf[1][ks], sacc[1][ntl], 0, 0, 0);
        }
      }

      bf16x8 pf0, pf1;
#pragma unroll
      for (int mt = 0; mt < 2; ++mt) {
        float p0, p1, p2, p3, p4, p5, p6, p7;
        if (av) {
          p0 = exp2c(sacc[mt][0][0]); p1 = exp2c(sacc[mt][0][1]);
          p2 = exp2c(sacc[mt][0][2]); p3 = exp2c(sacc[mt][0][3]);
          p4 = exp2c(sacc[mt][1][0]); p5 = exp2c(sacc[mt][1][1]);
          p6 = exp2c(sacc[mt][1][2]); p7 = exp2c(sacc[mt][1][3]);
        } else {
          f32x4 mq0 = *(const f32x4*)&Ml[(2 * kb + 0) * 16 + quad * 4];
          f32x4 mq1 = *(const f32x4*)&Ml[(2 * kb + 1) * 16 + quad * 4];
          p0 = exp2c(sacc[mt][0][0] + mq0[0]); p1 = exp2c(sacc[mt][0][1] + mq0[1]);
          p2 = exp2c(sacc[mt][0][2] + mq0[2]); p3 = exp2c(sacc[mt][0][3] + mq0[3]);
          p4 = exp2c(sacc[mt][1][0] + mq1[0]); p5 = exp2c(sacc[mt][1][1] + mq1[1]);
          p6 = exp2c(sacc[mt][1][2] + mq1[2]); p7 = exp2c(sacc[mt][1][3] + mq1[3]);
        }
        lsum[mt] += ((p0 + p1) + (p2 + p3)) + ((p4 + p5) + (p6 + p7));
        // pack (1 op each): pw0=keys(4q,4q+1) pw1=(4q+2,4q+3) pw2/3 = +16
        uint32_t pw0 = cvtpk(p0, p1), pw1 = cvtpk(p2, p3);
        uint32_t pw2 = cvtpk(p4, p5), pw3 = cvtpk(p6, p7);
        // rotate {laneb5, laneb4, wordb1}: permlane32_swap then permlane16_swap
        uint32x2 sA = __builtin_amdgcn_permlane32_swap(pw0, pw2, false, false);
        uint32x2 sB = __builtin_amdgcn_permlane32_swap(pw1, pw3, false, false);
        uint32x2 tA = __builtin_amdgcn_permlane16_swap(sA.x, sA.y, false, false);
        uint32x2 tB = __builtin_amdgcn_permlane16_swap(sB.x, sB.y, false, false);
        union { uint32_t u[4]; bf16x8 v; } pu;
        pu.u[0] = tA.x; pu.u[1] = tB.x; pu.u[2] = tA.y; pu.u[3] = tB.y;
        if (mt == 0) pf0 = pu.v; else pf1 = pu.v;
      }

#pragma unroll
      for (int dt = 0; dt < 4; ++dt) {
        bf16x8 vf = *(const bf16x8*)&Vt[dt * 2048 + lrow * 128 + (((kb * 4 + quad) ^ lrow) * 8)];
        acco[0][dt] = __builtin_amdgcn_mfma_f32_16x16x32_bf16(vf, pf0, acco[0][dt], 0, 0, 0);
        acco[1][dt] = __builtin_amdgcn_mfma_f32_16x16x32_bf16(vf, pf1, acco[1][dt], 0, 0, 0);
      }
    }

    __syncthreads();  // all waves done with Kl/Vt/Ml before next stage
    kcur += (size_t)128 * DIM;
    vcur += 128;
  }

  if (nsplit > 1) {
    // split path: store UNNORMALIZED f32 partial O + partial lsum
    const int sidx = blockIdx.z;
    float* obs = opart + ((size_t)(sidx * BSZ + b) * LQ) * DIM + h * HD;
    float* lps = lpart + ((size_t)(sidx * BSZ + b) * NH + h) * LQ;
#pragma unroll
    for (int mt = 0; mt < 2; ++mt) {
      float t = lsum[mt];
      t += __shfl_xor(t, 16);
      t += __shfl_xor(t, 32);
      int q = wq0 + mt * 16 + lrow;
      if (quad == 0) lps[q] = t;
#pragma unroll
      for (int dt = 0; dt < 4; ++dt)
        *(f32x4*)&obs[(size_t)q * DIM + dt * 16 + quad * 4] = acco[mt][dt];
    }
  } else {
    // fallback single-split path: normalized bf16 straight to op
    u16* ob = op + (size_t)b * LQ * DIM + h * HD;
#pragma unroll
    for (int mt = 0; mt < 2; ++mt) {
      float t = lsum[mt];
      t += __shfl_xor(t, 16);
      t += __shfl_xor(t, 32);
      float inv = t > 0.0f ? 1.0f / t : 0.0f;
      int q = wq0 + mt * 16 + lrow;
#pragma unroll
      for (int dt = 0; dt < 4; ++dt) {
        uint2 w;
        w.x = pk2r(acco[mt][dt][0] * inv, acco[mt][dt][1] * inv);
        w.y = pk2r(acco[mt][dt][2] * inv, acco[mt][dt][3] * inv);
        *(uint2*)&ob[(size_t)q * DIM + dt * 16 + quad * 4] = w;
      }
    }
  }
}

// ---------- split-K merge: ao = sum_s(O_s) / sum_s(l_s), bf16 ----------
__global__ void merge_splits(const float* __restrict__ opart,
                             const float* __restrict__ lpart,
                             u16* __restrict__ ao, int nsplit) {
  size_t e = ((size_t)blockIdx.x * blockDim.x + threadIdx.x) * 4;
  const size_t TOT = (size_t)BSZ * LQ * DIM;
  const size_t LSTRIDE = (size_t)BSZ * NH * LQ;
  if (e >= TOT) return;
  int col = (int)(e % DIM);
  int q = (int)((e / DIM) % LQ);
  int b = (int)(e / ((size_t)LQ * DIM));
  int h = col >> 6;
  size_t li = ((size_t)b * NH + h) * LQ + q;
  float l = 0.0f;
  f32x4 a = zero4();
  for (int s = 0; s < nsplit; ++s) {
    l += lpart[s * LSTRIDE + li];
    f32x4 c = *(const f32x4*)(opart + s * TOT + e);
    a[0] += c[0]; a[1] += c[1]; a[2] += c[2]; a[3] += c[3];
  }
  float inv = l > 0.0f ? 1.0f / l : 0.0f;
  uint2 w;
  w.x = pk2r(a[0] * inv, a[1] * inv);
  w.y = pk2r(a[2] * inv, a[3] * inv);
  *(uint2*)(ao + e) = w;
}

extern "C" void kernel_launch(void* const* d_in, const int* in_sizes, int n_in,
                              void* d_out, int out_size, void* d_ws, size_t ws_size,
                              hipStream_t stream) {
  (void)in_sizes; (void)n_in; (void)out_size;
  const int* kvmask = (const int*)d_in[3];

  u16* ws = (u16*)d_ws;
  const long long SQ = (long long)BSZ * LQ * DIM;   // 4194304
  const long long SW = (long long)DIM * DIM;
  const long long SB = DIM;
  long long cum[12];
  cum[0] = 0;
  cum[1] = cum[0] + SQ;    // q
  cum[2] = cum[1] + SQ;    // k
  cum[3] = cum[2] + SQ;    // v
  cum[4] = cum[3] + SW;    // Wq
  cum[5] = cum[4] + SW;    // Wk
  cum[6] = cum[5] + SW;    // Wv
  cum[7] = cum[6] + SW;    // Wo
  cum[8] = cum[7] + SB;    // bq
  cum[9] = cum[8] + SB;    // bk
  cum[10] = cum[9] + SB;   // bv
  cum[11] = cum[10] + SB;  // bo
  const long long canon_end = cum[11];              // 16781312
  u16* cq  = ws + cum[0];
  u16* ck  = ws + cum[1];
  u16* cv  = ws + cum[2];
  u16* cWq = ws + cum[3];
  u16* cWk = ws + cum[4];
  u16* cWv = ws + cum[5];
  u16* cWo = ws + cum[6];
  u16* cbq = ws + cum[7];
  u16* cbk = ws + cum[8];
  u16* cbv = ws + cum[9];
  u16* cbo = ws + cum[10];
  u16* qp  = ws + canon_end;
  u16* kp  = qp + SQ;
  u16* vpt = kp + SQ;      // [B][H][HD][LK]
  u16* ao  = vpt + SQ;
  int* allv = (int*)(ao + SQ);

  // split-K partials region (f32), after allv, 16B aligned
  uintptr_t fbase = (((uintptr_t)(allv + 4)) + 15) & ~(uintptr_t)15;
  float* opart = (float*)fbase;
  const size_t TOT = (size_t)BSZ * LQ * DIM;       // 4194304 floats per split
  const size_t LS  = (size_t)BSZ * NH * LQ;        // 65536 floats per split
  // choose largest nsplit in {4,2,1} that fits (opart laid out for nsplit)
  int nsplit = 1;
  {
    size_t base_off = fbase - (uintptr_t)d_ws;
    size_t need4 = base_off + 4 * (TOT + LS) * sizeof(float);
    size_t need2 = base_off + 2 * (TOT + LS) * sizeof(float);
    if (ws_size >= need4) nsplit = 4;
    else if (ws_size >= need2) nsplit = 2;
  }
  float* lpart = opart + (size_t)nsplit * TOT;

  hipMemsetAsync(allv, 0xFF, 2 * sizeof(int), stream);
  mask_allvalid<<<BSZ, 256, 0, stream>>>(kvmask, allv);

  ConvArgs ca;
  ca.src[0] = (const float*)d_in[0];   // q
  ca.src[1] = (const float*)d_in[1];   // k
  ca.src[2] = (const float*)d_in[2];   // v
  ca.src[3] = (const float*)d_in[4];   // Wq
  ca.src[4] = (const float*)d_in[6];   // Wk
  ca.src[5] = (const float*)d_in[8];   // Wv
  ca.src[6] = (const float*)d_in[10];  // Wo
  ca.src[7] = (const float*)d_in[5];   // bq
  ca.src[8] = (const float*)d_in[7];   // bk
  ca.src[9] = (const float*)d_in[9];   // bv
  ca.src[10] = (const float*)d_in[11]; // bo
  for (int i = 0; i < 12; ++i) ca.cum[i] = cum[i];
  ca.dst = ws;
  int conv_blocks = (int)((canon_end / 8 + 255) / 256);
  convert_inputs<<<conv_blocks, 256, 0, stream>>>(ca);

  const int M = BSZ * LQ;  // 4096

  GemmArgs g1;
  g1.X[0] = cq; g1.W[0] = cWq; g1.Bias[0] = cbq; g1.Y[0] = qp;
  g1.X[1] = ck; g1.W[1] = cWk; g1.Bias[1] = cbk; g1.Y[1] = kp;
  g1.X[2] = cv; g1.W[2] = cWv; g1.Bias[2] = cbv; g1.Y[2] = vpt;
  g1.osc[0] = SCALE_LOG2E;  // softmax scale+log2e folded into Q projection
  g1.osc[1] = 1.0f;
  g1.osc[2] = 1.0f;
  g1.f32out = 0;
  g1.vtz = 2;  // V output transposed via LDS, coalesced
  gemm_bt_bias<<<dim3(M / 128, DIM / 128, 3), dim3(256), 0, stream>>>(g1);

  attn_fused<<<dim3(LQ / 128, BSZ * NH, nsplit), dim3(256), 0, stream>>>(
      qp, kp, vpt, kvmask, allv, ao, opart, lpart, nsplit, LK / nsplit);
  if (nsplit > 1) {
    int mblocks = (int)((TOT / 4 + 255) / 256);
    merge_splits<<<mblocks, 256, 0, stream>>>(opart, lpart, ao, nsplit);
  }

  GemmArgs g2;
  g2.X[0] = ao; g2.W[0] = cWo; g2.Bias[0] = cbo; g2.Y[0] = d_out;
  g2.X[1] = ao; g2.W[1] = cWo; g2.Bias[1] = cbo; g2.Y[1] = d_out;
  g2.X[2] = ao; g2.W[2] = cWo; g2.Bias[2] = cbo; g2.Y[2] = d_out;
  g2.osc[0] = 1.0f; g2.osc[1] = 1.0f; g2.osc[2] = 1.0f;
  g2.f32out = 1;   // final output is FP32
  g2.vtz = -1;
  gemm_bt_bias<<<dim3(M / 128, DIM / 128, 1), dim3(256), 0, stream>>>(g2);
}

// Round 11
// 243.333 us; speedup vs baseline: 1.0744x; 1.0744x over previous
//
#include <hip/hip_runtime.h>
#include <stdint.h>

typedef unsigned short u16;
typedef __attribute__((ext_vector_type(8))) __bf16 bf16x8;
typedef __attribute__((ext_vector_type(4))) float f32x4;
typedef __attribute__((ext_vector_type(2))) unsigned int uint32x2;

#define DIM 1024
#define NH 16
#define HD 64
#define BSZ 2
#define LQ 2048
#define LK 2048
// SCALE * log2(e) = 0.125 * 1.4426950408889634
#define SCALE_LOG2E 0.18033688011112043f
#define MNEG -3.0e38f

// DTYPE TRUTH (established rounds 1-8): d_in float tensors and d_out are
// FP32. Reading them as bf16 produces NaN-pattern u16s (rounds 1,7,8 NaN).
// Internal pipeline is bf16 via an explicit convert pass.

static __device__ __forceinline__ float b2f(u16 u) {
  union { uint32_t i; float f; } v; v.i = ((uint32_t)u) << 16; return v.f;
}
static __device__ __forceinline__ u16 f2b(float f) {
  uint32_t x = __float_as_uint(f);
  return (u16)((x + 0x7fffu + ((x >> 16) & 1u)) >> 16);
}
// bf16 pair pack, round-half-up: 2 adds + 1 v_perm_b32 (validated r5-r6)
static __device__ __forceinline__ uint32_t pk2r(float lo, float hi) {
  uint32_t a = __float_as_uint(lo) + 0x8000u;
  uint32_t b = __float_as_uint(hi) + 0x8000u;
  return __builtin_amdgcn_perm(b, a, 0x07060302u);  // lo16=a[31:16], hi16=b[31:16]
}
// single-instruction packed f32->bf16x2 (RNE). Plain VOP3, no hazard. (R10)
static __device__ __forceinline__ uint32_t cvtpk(float lo, float hi) {
  uint32_t r;
  asm("v_cvt_pk_bf16_f32 %0, %1, %2" : "=v"(r) : "v"(lo), "v"(hi));
  return r;
}
static __device__ __forceinline__ f32x4 zero4() {
  f32x4 z; z[0] = 0.f; z[1] = 0.f; z[2] = 0.f; z[3] = 0.f; return z;
}
// exp2 via raw v_exp_f32 (library exp2f = ~10+ instrs of fixup; R4).
// s_nop inside the asm covers the TRANS->consumer 1-waitstate hazard.
// fmin guard: inf insurance; masked -3e38 still -> 0 exactly.
static __device__ __forceinline__ float exp2c(float s) {
  float r;
  asm("v_exp_f32 %0, %1\n\ts_nop 0" : "=v"(r) : "v"(fminf(s, 30.0f)));
  return r;
}
// async global->LDS, 16B/lane; LDS dest is wave-uniform base + lane*16
static __device__ __forceinline__ void gload_lds16(const u16* g, u16* l) {
  __builtin_amdgcn_global_load_lds(
      (const __attribute__((address_space(1))) void*)g,
      (__attribute__((address_space(3))) void*)l, 16, 0, 0);
}

// ---------- kv_mask all-valid reduction (per batch) ----------
__global__ void mask_allvalid(const int* __restrict__ kvmask, int* allv) {
  int b = blockIdx.x;
  int base = b * LK + threadIdx.x * 8;
  int ok = 1;
#pragma unroll
  for (int j = 0; j < 8; ++j) ok &= (kvmask[base + j] != 0);
  unsigned long long m = __ballot(ok != 0);
  if ((threadIdx.x & 63) == 0 && m != ~0ULL) atomicAnd(&allv[b], 0);
}

// ---------- input canonicalization: fp32 -> bf16 in ws ----------
struct ConvArgs {
  const float* src[11];
  long long cum[12];   // cumulative element offsets (all sizes % 8 == 0)
  u16* dst;
};

__global__ void convert_inputs(ConvArgs ca) {
  long long c = (long long)blockIdx.x * blockDim.x + threadIdx.x;
  long long e0 = c * 8;
  if (e0 >= ca.cum[11]) return;
  int s = 0;
  while (e0 >= ca.cum[s + 1]) ++s;
  const float* sp = ca.src[s] + (e0 - ca.cum[s]);
  union { uint4 v; uint32_t w[4]; } t;
#pragma unroll
  for (int j = 0; j < 4; ++j) t.w[j] = pk2r(sp[2 * j], sp[2 * j + 1]);
  *(uint4*)(ca.dst + e0) = t.v;
}

// ---------- GEMM: Y[m,n] = (sum_k X[m,k]*W[n,k] + bias[n]) * osc ----------
// 128x128 tile, BK=64, 4 waves 2x2, global_load_lds width-16 staging (m97).
//
// R11: (256,2) -> (256,3). Session lesson (R6-R9): launch_bounds' wpEU
// governs residency; largest spill-free value wins. GEMM1 is 768 blocks:
// at 2/CU = 1.5 dispatch rounds (half-empty tail); at 3/CU = ONE round,
// and 3 waves/SIMD hide latency better. LDS 34.8KB x3 = 104KB < 160KB.
// Reg estimate: acc 64 (acc file) + af/bfr 32 + addr/epilogue ~30 = ~126
// <= 170 budget (m97's 164 was an unconstrained-allocator choice; attn
// compressed 92->84 under a cap). Spill tripwire: gemm WRITE_SIZE balloon.
struct GemmArgs {
  const u16* X[3];
  const u16* W[3];
  const u16* Bias[3];
  void* Y[3];
  float osc[3];      // output scale; SCALE_LOG2E for Q (softmax in log2 domain)
  int f32out;        // 1 => Y is float* (final output), else bf16 u16*
  int vtz;           // z index whose output is stored as [b][h][d][key]
};

__global__ __launch_bounds__(256, 3) void gemm_bt_bias(GemmArgs ga) {
  const int K = DIM, N = DIM;
  __shared__ u16 smem[17408];          // Al(8K u16) + Bl(8K u16) | VT(128x136)
  u16* const Al = smem;
  u16* const Bl = smem + 8192;
  const int tid = threadIdx.x;
  const int wave = tid >> 6, lane = tid & 63;
  const int wm = wave >> 1, wn = wave & 1;
  const int lrow = lane & 15, quad = lane >> 4;
  const int z = blockIdx.z;
  const u16* X = ga.X[z];
  const u16* W = ga.W[z];
  const u16* Bias = ga.Bias[z];
  const float osc = ga.osc[z];
  const int m0 = blockIdx.x * 128;
  const int n0 = blockIdx.y * 128;

  f32x4 acc[4][4];
#pragma unroll
  for (int i = 0; i < 4; ++i)
#pragma unroll
    for (int j = 0; j < 4; ++j) acc[i][j] = zero4();

  const int cbase = wave * 256;
  for (int k0 = 0; k0 < K; k0 += 64) {
    __syncthreads();  // previous tile fully consumed
#pragma unroll
    for (int i = 0; i < 4; ++i) {
      int c = cbase + i * 64 + lane;       // chunk id, 16B each
      int row = c >> 3, colb = c & 7;
      gload_lds16(X + (size_t)(m0 + row) * K + k0 + colb * 8,
                  &Al[(cbase + i * 64) * 8]);
      gload_lds16(W + (size_t)(n0 + row) * K + k0 + colb * 8,
                  &Bl[(cbase + i * 64) * 8]);
    }
    __syncthreads();  // barrier drains vmcnt -> staged data visible
#pragma unroll
    for (int ks = 0; ks < 2; ++ks) {
      bf16x8 af[4], bfr[4];
#pragma unroll
      for (int t = 0; t < 4; ++t)
        af[t] = *(const bf16x8*)&Al[(wm * 64 + t * 16 + lrow) * 64 + ks * 32 + quad * 8];
#pragma unroll
      for (int t = 0; t < 4; ++t)
        bfr[t] = *(const bf16x8*)&Bl[(wn * 64 + t * 16 + lrow) * 64 + ks * 32 + quad * 8];
#pragma unroll
      for (int mt = 0; mt < 4; ++mt)
#pragma unroll
        for (int nt = 0; nt < 4; ++nt)
          acc[mt][nt] = __builtin_amdgcn_mfma_f32_16x16x32_bf16(af[mt], bfr[nt], acc[mt][nt], 0, 0, 0);
    }
  }

  if (z == ga.vtz) {
    // V projection -> [b][h][d][key]: transpose tile in LDS, coalesced store
    u16* Yv = (u16*)ga.Y[z];
    u16* const VT = smem;  // [128 cols][136 pad] u16
    __syncthreads();       // all waves done reading Al/Bl
#pragma unroll
    for (int nt = 0; nt < 4; ++nt) {
      int colL = wn * 64 + nt * 16 + lrow;
      float bv = b2f(Bias[n0 + colL]);
#pragma unroll
      for (int mt = 0; mt < 4; ++mt) {
        int keyL = wm * 64 + mt * 16 + quad * 4;
        uint2 w;
        w.x = pk2r((acc[mt][nt][0] + bv) * osc, (acc[mt][nt][1] + bv) * osc);
        w.y = pk2r((acc[mt][nt][2] + bv) * osc, (acc[mt][nt][3] + bv) * osc);
        *(uint2*)&VT[colL * 136 + keyL] = w;
      }
    }
    __syncthreads();
    const int bb = m0 >> 11, key0 = m0 & 2047;
#pragma unroll
    for (int i = 0; i < 8; ++i) {       // 8*256 = 2048 chunks = full 128x128
      int c = i * 256 + tid;
      int colL = c >> 4, k8 = c & 15;
      int hh = (n0 + colL) >> 6, dd = (n0 + colL) & 63;
      *(uint4*)(Yv + ((size_t)(bb * NH + hh) * HD + dd) * LK + key0 + k8 * 8) =
          *(const uint4*)&VT[colL * 136 + k8 * 8];
    }
  } else if (ga.f32out) {
    float* Yf = (float*)ga.Y[z];
#pragma unroll
    for (int nt = 0; nt < 4; ++nt) {
      int col = n0 + wn * 64 + nt * 16 + lrow;
      float bv = b2f(Bias[col]);
#pragma unroll
      for (int mt = 0; mt < 4; ++mt) {
        int rowb = m0 + wm * 64 + mt * 16 + quad * 4;
#pragma unroll
        for (int r = 0; r < 4; ++r)
          Yf[(size_t)(rowb + r) * N + col] = (acc[mt][nt][r] + bv) * osc;
      }
    }
  } else {
    u16* Yv = (u16*)ga.Y[z];
#pragma unroll
    for (int nt = 0; nt < 4; ++nt) {
      int col = n0 + wn * 64 + nt * 16 + lrow;
      float bv = b2f(Bias[col]);
#pragma unroll
      for (int mt = 0; mt < 4; ++mt) {
        int rowb = m0 + wm * 64 + mt * 16 + quad * 4;
#pragma unroll
        for (int r = 0; r < 4; ++r)
          Yv[(size_t)(rowb + r) * N + col] = f2b((acc[mt][nt][r] + bv) * osc);
      }
    }
  }
}

// ---------- fused flash attention (S^T formulation, no-max softmax) ----------
// 1 block per (b, h, 128 q rows, key-split); 4 waves x 32 q rows; 128-key
// chunks. Q pre-scaled by SCALE*log2e -> sacc is log2-domain; |s| <~ 3 so
// fixed-max softmax is safe: p = exp2(s); masked keys add -3e38 -> p = 0.
//
// R11: nsplit reverted 4 -> 2 (R10 showed nsplit=4 nets negative at the
// pipeline level: merge traffic doubles + Q re-fetch outweigh the 2us attn
// gain). Keeps cvtpk pack (1 VALU op), async gload_lds staging, both-sides
// XOR swizzle (0 bank conflicts), (256,3) = largest spill-free residency.
__global__ __launch_bounds__(256, 3) void attn_fused(
    const u16* __restrict__ qp, const u16* __restrict__ kp,
    const u16* __restrict__ vpt, const int* __restrict__ kvmask,
    const int* __restrict__ allv, u16* __restrict__ op,
    float* __restrict__ opart, float* __restrict__ lpart,
    int nsplit, int kspan) {
  __shared__ u16 Kl[128 * 64];        // K chunk [key][d], LINEAR, XOR-swizzled
  __shared__ u16 Vt[64 * 128];        // V^T chunk [d][key], LINEAR, XOR-swizzled
  __shared__ float Ml[128];           // additive mask per key (masked path)
  const int tid = threadIdx.x;
  const int wave = tid >> 6, lane = tid & 63;
  const int lrow = lane & 15, quad = lane >> 4;
  const int bh = blockIdx.y;
  const int b = bh >> 4, h = bh & 15;
  const int q0 = blockIdx.x * 128;
  const int kc0 = blockIdx.z * kspan;
  const int kcend = kc0 + kspan;
  const bool av = (allv[b] != 0);     // wave-uniform

  const u16* qbase = qp + (size_t)b * LQ * DIM + h * HD;
  const u16* kbase = kp + (size_t)b * LK * DIM + h * HD;
  const u16* vtb = vpt + (size_t)(b * NH + h) * HD * LK;  // [64][2048]
  const int* mbase = kvmask + b * LK;
  const int wq0 = q0 + wave * 32;

  // Q as B-operand frags: B[k=d=quad*8+j][n=q=lrow]
  bf16x8 qf[2][2];
#pragma unroll
  for (int mt = 0; mt < 2; ++mt)
#pragma unroll
    for (int ks = 0; ks < 2; ++ks)
      qf[mt][ks] = *(const bf16x8*)(qbase + (size_t)(wq0 + mt * 16 + lrow) * DIM + ks * 32 + quad * 8);

  f32x4 acco[2][4];
  float lsum[2];
#pragma unroll
  for (int mt = 0; mt < 2; ++mt) {
#pragma unroll
    for (int dt = 0; dt < 4; ++dt) acco[mt][dt] = zero4();
    lsum[mt] = 0.0f;
  }

  // --- staging geometry (all per-thread constants) ---
  // K: instr i covers rows (i*4+wave)*8 + (lane>>3); lane unit u=lane&7,
  //    swizzled source column (u ^ (lane>>3)) since row&7 == lane>>3.
  const u16* kcur = kbase + (size_t)kc0 * DIM
      + (size_t)(wave * 8 + (lane >> 3)) * DIM + (((lane & 7) ^ (lane >> 3)) * 8);
  // V: instr i covers rows (i*4+wave)*4 + (lane>>4); unit u=lane&15,
  //    d&15 == (4*wave + (lane>>4)) & 15 for all i (16i == 0 mod 16).
  const u16* vcur = vtb + kc0
      + (size_t)(wave * 4 + (lane >> 4)) * LK
      + (((lane & 15) ^ ((4 * wave + (lane >> 4)) & 15)) * 8);
  u16* const Kldst = &Kl[wave * 512];   // + i*2048 per instr
  u16* const Vtdst = &Vt[wave * 512];
  // read-side swizzled column bases (u16 units)
  const int kread0 = lrow * 64 + ((quad ^ (lrow & 7)) * 8);
  const int kread1 = lrow * 64 + (((4 + quad) ^ (lrow & 7)) * 8);

  for (int kc = kc0; kc < kcend; kc += 128) {
    // ---- async staging: 8 gload_lds16/thread, ZERO staging VGPRs ----
    gload_lds16(kcur,                       Kldst);
    gload_lds16(kcur + (size_t)32 * DIM,    Kldst + 2048);
    gload_lds16(kcur + (size_t)64 * DIM,    Kldst + 4096);
    gload_lds16(kcur + (size_t)96 * DIM,    Kldst + 6144);
    gload_lds16(vcur,                       Vtdst);
    gload_lds16(vcur + (size_t)16 * LK,     Vtdst + 2048);
    gload_lds16(vcur + (size_t)32 * LK,     Vtdst + 4096);
    gload_lds16(vcur + (size_t)48 * LK,     Vtdst + 6144);
    if (!av && tid < 128) Ml[tid] = mbase[kc + tid] ? 0.0f : MNEG;
    __syncthreads();  // drains vmcnt+lgkm -> staged chunk visible

    // ---- fused S + softmax + PV per 32-key block; P stays in registers ----
#pragma unroll
    for (int kb = 0; kb < 4; ++kb) {
      f32x4 sacc[2][2];
#pragma unroll
      for (int mt = 0; mt < 2; ++mt)
#pragma unroll
        for (int ntl = 0; ntl < 2; ++ntl) sacc[mt][ntl] = zero4();
#pragma unroll
      for (int ks = 0; ks < 2; ++ks) {
#pragma unroll
        for (int ntl = 0; ntl < 2; ++ntl) {
          bf16x8 kf = *(const bf16x8*)&Kl[(2 * kb + ntl) * 1024 + (ks ? kread1 : kread0)];
          sacc[0][ntl] = __builtin_amdgcn_mfma_f32_16x16x32_bf16(kf, qf[0][ks], sacc[0][ntl], 0, 0, 0);
          sacc[1][ntl] = __builtin_amdgcn_mfma_f32_16x16x32_bf16(kf, qf[1][ks], sacc[1][ntl], 0, 0, 0);
        }
      }

      bf16x8 pf0, pf1;
#pragma unroll
      for (int mt = 0; mt < 2; ++mt) {
        float p0, p1, p2, p3, p4, p5, p6, p7;
        if (av) {
          p0 = exp2c(sacc[mt][0][0]); p1 = exp2c(sacc[mt][0][1]);
          p2 = exp2c(sacc[mt][0][2]); p3 = exp2c(sacc[mt][0][3]);
          p4 = exp2c(sacc[mt][1][0]); p5 = exp2c(sacc[mt][1][1]);
          p6 = exp2c(sacc[mt][1][2]); p7 = exp2c(sacc[mt][1][3]);
        } else {
          f32x4 mq0 = *(const f32x4*)&Ml[(2 * kb + 0) * 16 + quad * 4];
          f32x4 mq1 = *(const f32x4*)&Ml[(2 * kb + 1) * 16 + quad * 4];
          p0 = exp2c(sacc[mt][0][0] + mq0[0]); p1 = exp2c(sacc[mt][0][1] + mq0[1]);
          p2 = exp2c(sacc[mt][0][2] + mq0[2]); p3 = exp2c(sacc[mt][0][3] + mq0[3]);
          p4 = exp2c(sacc[mt][1][0] + mq1[0]); p5 = exp2c(sacc[mt][1][1] + mq1[1]);
          p6 = exp2c(sacc[mt][1][2] + mq1[2]); p7 = exp2c(sacc[mt][1][3] + mq1[3]);
        }
        lsum[mt] += ((p0 + p1) + (p2 + p3)) + ((p4 + p5) + (p6 + p7));
        // pack (1 op each): pw0=keys(4q,4q+1) pw1=(4q+2,4q+3) pw2/3 = +16
        uint32_t pw0 = cvtpk(p0, p1), pw1 = cvtpk(p2, p3);
        uint32_t pw2 = cvtpk(p4, p5), pw3 = cvtpk(p6, p7);
        // rotate {laneb5, laneb4, wordb1}: permlane32_swap then permlane16_swap
        uint32x2 sA = __builtin_amdgcn_permlane32_swap(pw0, pw2, false, false);
        uint32x2 sB = __builtin_amdgcn_permlane32_swap(pw1, pw3, false, false);
        uint32x2 tA = __builtin_amdgcn_permlane16_swap(sA.x, sA.y, false, false);
        uint32x2 tB = __builtin_amdgcn_permlane16_swap(sB.x, sB.y, false, false);
        union { uint32_t u[4]; bf16x8 v; } pu;
        pu.u[0] = tA.x; pu.u[1] = tB.x; pu.u[2] = tA.y; pu.u[3] = tB.y;
        if (mt == 0) pf0 = pu.v; else pf1 = pu.v;
      }

#pragma unroll
      for (int dt = 0; dt < 4; ++dt) {
        bf16x8 vf = *(const bf16x8*)&Vt[dt * 2048 + lrow * 128 + (((kb * 4 + quad) ^ lrow) * 8)];
        acco[0][dt] = __builtin_amdgcn_mfma_f32_16x16x32_bf16(vf, pf0, acco[0][dt], 0, 0, 0);
        acco[1][dt] = __builtin_amdgcn_mfma_f32_16x16x32_bf16(vf, pf1, acco[1][dt], 0, 0, 0);
      }
    }

    __syncthreads();  // all waves done with Kl/Vt/Ml before next stage
    kcur += (size_t)128 * DIM;
    vcur += 128;
  }

  if (nsplit > 1) {
    // split path: store UNNORMALIZED f32 partial O + partial lsum
    const int sidx = blockIdx.z;
    float* obs = opart + ((size_t)(sidx * BSZ + b) * LQ) * DIM + h * HD;
    float* lps = lpart + ((size_t)(sidx * BSZ + b) * NH + h) * LQ;
#pragma unroll
    for (int mt = 0; mt < 2; ++mt) {
      float t = lsum[mt];
      t += __shfl_xor(t, 16);
      t += __shfl_xor(t, 32);
      int q = wq0 + mt * 16 + lrow;
      if (quad == 0) lps[q] = t;
#pragma unroll
      for (int dt = 0; dt < 4; ++dt)
        *(f32x4*)&obs[(size_t)q * DIM + dt * 16 + quad * 4] = acco[mt][dt];
    }
  } else {
    // fallback single-split path: normalized bf16 straight to op
    u16* ob = op + (size_t)b * LQ * DIM + h * HD;
#pragma unroll
    for (int mt = 0; mt < 2; ++mt) {
      float t = lsum[mt];
      t += __shfl_xor(t, 16);
      t += __shfl_xor(t, 32);
      float inv = t > 0.0f ? 1.0f / t : 0.0f;
      int q = wq0 + mt * 16 + lrow;
#pragma unroll
      for (int dt = 0; dt < 4; ++dt) {
        uint2 w;
        w.x = pk2r(acco[mt][dt][0] * inv, acco[mt][dt][1] * inv);
        w.y = pk2r(acco[mt][dt][2] * inv, acco[mt][dt][3] * inv);
        *(uint2*)&ob[(size_t)q * DIM + dt * 16 + quad * 4] = w;
      }
    }
  }
}

// ---------- split-K merge: ao = sum_s(O_s) / sum_s(l_s), bf16 ----------
__global__ void merge_splits(const float* __restrict__ opart,
                             const float* __restrict__ lpart,
                             u16* __restrict__ ao, int nsplit) {
  size_t e = ((size_t)blockIdx.x * blockDim.x + threadIdx.x) * 4;
  const size_t TOT = (size_t)BSZ * LQ * DIM;
  const size_t LSTRIDE = (size_t)BSZ * NH * LQ;
  if (e >= TOT) return;
  int col = (int)(e % DIM);
  int q = (int)((e / DIM) % LQ);
  int b = (int)(e / ((size_t)LQ * DIM));
  int h = col >> 6;
  size_t li = ((size_t)b * NH + h) * LQ + q;
  float l = 0.0f;
  f32x4 a = zero4();
  for (int s = 0; s < nsplit; ++s) {
    l += lpart[s * LSTRIDE + li];
    f32x4 c = *(const f32x4*)(opart + s * TOT + e);
    a[0] += c[0]; a[1] += c[1]; a[2] += c[2]; a[3] += c[3];
  }
  float inv = l > 0.0f ? 1.0f / l : 0.0f;
  uint2 w;
  w.x = pk2r(a[0] * inv, a[1] * inv);
  w.y = pk2r(a[2] * inv, a[3] * inv);
  *(uint2*)(ao + e) = w;
}

extern "C" void kernel_launch(void* const* d_in, const int* in_sizes, int n_in,
                              void* d_out, int out_size, void* d_ws, size_t ws_size,
                              hipStream_t stream) {
  (void)in_sizes; (void)n_in; (void)out_size;
  const int* kvmask = (const int*)d_in[3];

  u16* ws = (u16*)d_ws;
  const long long SQ = (long long)BSZ * LQ * DIM;   // 4194304
  const long long SW = (long long)DIM * DIM;
  const long long SB = DIM;
  long long cum[12];
  cum[0] = 0;
  cum[1] = cum[0] + SQ;    // q
  cum[2] = cum[1] + SQ;    // k
  cum[3] = cum[2] + SQ;    // v
  cum[4] = cum[3] + SW;    // Wq
  cum[5] = cum[4] + SW;    // Wk
  cum[6] = cum[5] + SW;    // Wv
  cum[7] = cum[6] + SW;    // Wo
  cum[8] = cum[7] + SB;    // bq
  cum[9] = cum[8] + SB;    // bk
  cum[10] = cum[9] + SB;   // bv
  cum[11] = cum[10] + SB;  // bo
  const long long canon_end = cum[11];              // 16781312
  u16* cq  = ws + cum[0];
  u16* ck  = ws + cum[1];
  u16* cv  = ws + cum[2];
  u16* cWq = ws + cum[3];
  u16* cWk = ws + cum[4];
  u16* cWv = ws + cum[5];
  u16* cWo = ws + cum[6];
  u16* cbq = ws + cum[7];
  u16* cbk = ws + cum[8];
  u16* cbv = ws + cum[9];
  u16* cbo = ws + cum[10];
  u16* qp  = ws + canon_end;
  u16* kp  = qp + SQ;
  u16* vpt = kp + SQ;      // [B][H][HD][LK]
  u16* ao  = vpt + SQ;
  int* allv = (int*)(ao + SQ);

  // split-K partials region (f32), after allv, 16B aligned
  uintptr_t fbase = (((uintptr_t)(allv + 4)) + 15) & ~(uintptr_t)15;
  float* opart = (float*)fbase;
  const size_t TOT = (size_t)BSZ * LQ * DIM;       // 4194304 floats per split
  const size_t LS  = (size_t)BSZ * NH * LQ;        // 65536 floats per split
  // R11: nsplit=2 preferred (R10: nsplit=4 nets negative -- merge traffic)
  int nsplit = 1;
  {
    size_t base_off = fbase - (uintptr_t)d_ws;
    size_t need2 = base_off + 2 * (TOT + LS) * sizeof(float);
    if (ws_size >= need2) nsplit = 2;
  }
  float* lpart = opart + (size_t)nsplit * TOT;

  hipMemsetAsync(allv, 0xFF, 2 * sizeof(int), stream);
  mask_allvalid<<<BSZ, 256, 0, stream>>>(kvmask, allv);

  ConvArgs ca;
  ca.src[0] = (const float*)d_in[0];   // q
  ca.src[1] = (const float*)d_in[1];   // k
  ca.src[2] = (const float*)d_in[2];   // v
  ca.src[3] = (const float*)d_in[4];   // Wq
  ca.src[4] = (const float*)d_in[6];   // Wk
  ca.src[5] = (const float*)d_in[8];   // Wv
  ca.src[6] = (const float*)d_in[10];  // Wo
  ca.src[7] = (const float*)d_in[5];   // bq
  ca.src[8] = (const float*)d_in[7];   // bk
  ca.src[9] = (const float*)d_in[9];   // bv
  ca.src[10] = (const float*)d_in[11]; // bo
  for (int i = 0; i < 12; ++i) ca.cum[i] = cum[i];
  ca.dst = ws;
  int conv_blocks = (int)((canon_end / 8 + 255) / 256);
  convert_inputs<<<conv_blocks, 256, 0, stream>>>(ca);

  const int M = BSZ * LQ;  // 4096

  GemmArgs g1;
  g1.X[0] = cq; g1.W[0] = cWq; g1.Bias[0] = cbq; g1.Y[0] = qp;
  g1.X[1] = ck; g1.W[1] = cWk; g1.Bias[1] = cbk; g1.Y[1] = kp;
  g1.X[2] = cv; g1.W[2] = cWv; g1.Bias[2] = cbv; g1.Y[2] = vpt;
  g1.osc[0] = SCALE_LOG2E;  // softmax scale+log2e folded into Q projection
  g1.osc[1] = 1.0f;
  g1.osc[2] = 1.0f;
  g1.f32out = 0;
  g1.vtz = 2;  // V output transposed via LDS, coalesced
  gemm_bt_bias<<<dim3(M / 128, DIM / 128, 3), dim3(256), 0, stream>>>(g1);

  attn_fused<<<dim3(LQ / 128, BSZ * NH, nsplit), dim3(256), 0, stream>>>(
      qp, kp, vpt, kvmask, allv, ao, opart, lpart, nsplit, LK / nsplit);
  if (nsplit > 1) {
    int mblocks = (int)((TOT / 4 + 255) / 256);
    merge_splits<<<mblocks, 256, 0, stream>>>(opart, lpart, ao, nsplit);
  }

  GemmArgs g2;
  g2.X[0] = ao; g2.W[0] = cWo; g2.Bias[0] = cbo; g2.Y[0] = d_out;
  g2.X[1] = ao; g2.W[1] = cWo; g2.Bias[1] = cbo; g2.Y[1] = d_out;
  g2.X[2] = ao; g2.W[2] = cWo; g2.Bias[2] = cbo; g2.Y[2] = d_out;
  g2.osc[0] = 1.0f; g2.osc[1] = 1.0f; g2.osc[2] = 1.0f;
  g2.f32out = 1;   // final output is FP32
  g2.vtz = -1;
  gemm_bt_bias<<<dim3(M / 128, DIM / 128, 1), dim3(256), 0, stream>>>(g2);
}